// Round 1
// baseline (137.063 us; speedup 1.0000x reference)
//
#include <hip/hip_runtime.h>
#include <hip/hip_bf16.h>

typedef __bf16 bf16;
typedef __attribute__((ext_vector_type(8))) __bf16 bf16x8;
typedef __attribute__((ext_vector_type(4))) __bf16 bf16x4;
typedef __attribute__((ext_vector_type(4))) float f32x4;

static constexpr int NSEQ = 4;
static constexpr int LQ   = 512;
static constexpr int HQN  = 32;
static constexpr int HKVN = 8;
static constexpr int GQ   = 4;
static constexpr int DH   = 128;
static constexpr int BPS  = 64;     // blocks per sequence (2048/32)
static constexpr int SKV  = 2048;   // max kv length
static constexpr int KVB  = 64;     // kv tile (2 paged blocks)
static constexpr int QBL  = 32;     // l-rows per workgroup (per wave, 1 g head each)

__device__ __forceinline__ bf16x8 cvt8(const float4& a, const float4& b) {
  bf16x8 o;
  o[0] = (bf16)a.x; o[1] = (bf16)a.y; o[2] = (bf16)a.z; o[3] = (bf16)a.w;
  o[4] = (bf16)b.x; o[5] = (bf16)b.y; o[6] = (bf16)b.z; o[7] = (bf16)b.w;
  return o;
}

// prepass 1: gather paged K + convert to bf16: kb[b][h][s][d]
__global__ void prep_k(const float* __restrict__ kc, const int* __restrict__ bt,
                       bf16* __restrict__ kb) {
  int e = (blockIdx.x * 256 + threadIdx.x) * 8;   // 8 elems / thread
  int d = e & 127;
  int s = (e >> 7) & 2047;
  int h = (e >> 18) & 7;
  int b = e >> 21;
  int pb = bt[b * BPS + (s >> 5)];
  const float* src = kc + (((size_t)pb * 32 + (s & 31)) * 8 + h) * 128 + d;
  float4 a = *(const float4*)src;
  float4 c = *(const float4*)(src + 4);
  *(bf16x8*)(kb + e) = cvt8(a, c);
}

// prepass 2: gather paged V + convert + transpose: vt[b][h][d][s]
__global__ void prep_vt(const float* __restrict__ vc, const int* __restrict__ bt,
                        bf16* __restrict__ vt) {
  __shared__ __align__(16) bf16 T[64][136];
  int bid = blockIdx.x;          // 4*8*32 = 1024 blocks
  int st = bid & 31;
  int h  = (bid >> 5) & 7;
  int b  = bid >> 8;
  int tid = threadIdx.x;
  {
    int s  = tid >> 2;
    int d0 = (tid & 3) * 32;
    int sg = st * 64 + s;
    int pb = bt[b * BPS + (sg >> 5)];
    const float* src = vc + (((size_t)pb * 32 + (sg & 31)) * 8 + h) * 128 + d0;
#pragma unroll
    for (int k = 0; k < 4; ++k) {
      float4 a = *(const float4*)(src + 8 * k);
      float4 c = *(const float4*)(src + 8 * k + 4);
      *(bf16x8*)&T[s][d0 + 8 * k] = cvt8(a, c);
    }
  }
  __syncthreads();
  {
    int d  = tid & 127;
    int g2 = tid >> 7;
    bf16* dst = vt + (((size_t)(b * 8 + h)) * 128 + d) * SKV + st * 64 + g2 * 32;
#pragma unroll
    for (int k = 0; k < 4; ++k) {
      bf16x8 o;
#pragma unroll
      for (int j = 0; j < 8; ++j) o[j] = T[g2 * 32 + k * 8 + j][d];
      *(bf16x8*)(dst + 8 * k) = o;
    }
  }
}

// flash attention: 1 workgroup = (b, h, 32 l-rows); wave w handles GQA head g = w.
// Swapped QK^T (A=K, B=Q) -> S^T; softmax in-register; P through per-wave LDS;
// PV with A=P, B=V^T from LDS. 16x16x32 bf16 MFMA, f32 accum.
template <bool WS>
__global__ __launch_bounds__(256, 2)
void attn_kern(const float* __restrict__ q, const float* __restrict__ kc,
               const float* __restrict__ vc, const int* __restrict__ bt,
               const int* __restrict__ seq_lens, const bf16* __restrict__ kb,
               const bf16* __restrict__ vtb, float* __restrict__ out) {
  __shared__ __align__(16) bf16 Kl[64][136];      // [s][d], pad -> 2-way max
  __shared__ __align__(16) bf16 Vl[128][72];      // [d][s] (transposed V)
  __shared__ __align__(16) bf16 Pl[4][32][72];    // per wave [q][s]

  int bid = (int)blockIdx.x;
  bid = (bid & 7) * 64 + (bid >> 3);   // XCD swizzle: 16 qtiles of one (b,h) share an XCD L2
  int qt = bid & 15;
  int h  = (bid >> 4) & 7;
  int b  = bid >> 7;
  int lb = qt * QBL;

  int tid  = (int)threadIdx.x;
  int w    = tid >> 6;       // g head
  int lane = tid & 63;
  int lq   = lane & 15;
  int lg   = lane >> 4;

  int ctx = seq_lens[b] - LQ;                       // 1536
  int nt  = (ctx + lb + QBL + KVB - 1) / KVB;       // kv tiles needed (causal)

  const float CEXP = 0.08838834764831843f * 1.44269504088896340f;  // scale*log2(e)

  // Q fragments (B-operand): lane holds Q[lb + n*16 + lq][kk*32 + lg*8 + j]
  int hq = h * GQ + w;
  bf16x8 qf[2][4];
#pragma unroll
  for (int n = 0; n < 2; ++n) {
    const float* qp = q + (((size_t)(b * LQ + lb + n * 16 + lq)) * HQN + hq) * DH + lg * 8;
#pragma unroll
    for (int kk = 0; kk < 4; ++kk) {
      float4 a = *(const float4*)(qp + kk * 32);
      float4 c = *(const float4*)(qp + kk * 32 + 4);
      qf[n][kk] = cvt8(a, c);
    }
  }

  f32x4 accO[2][8];
  f32x4 zero = {0.f, 0.f, 0.f, 0.f};
#pragma unroll
  for (int m = 0; m < 2; ++m)
#pragma unroll
    for (int nd = 0; nd < 8; ++nd) accO[m][nd] = zero;
  float mrun[2] = {-1e30f, -1e30f};
  float lrun[2] = {0.f, 0.f};

  const int* btr = bt + b * BPS;

  for (int t = 0; t < nt; ++t) {
    // ---- stage K [64][128] and V^T [128][64] tiles into LDS ----
    if (WS) {
      const bf16* ks = kb + (((size_t)(b * 8 + h)) * SKV + t * 64) * DH;
      int s  = tid >> 2;
      int d0 = (tid & 3) * 32;
#pragma unroll
      for (int k = 0; k < 4; ++k)
        *(bf16x8*)&Kl[s][d0 + 8 * k] = *(const bf16x8*)(ks + s * DH + d0 + 8 * k);
      const bf16* vs = vtb + (((size_t)(b * 8 + h)) * DH) * SKV + t * 64;
      int d   = tid >> 1;
      int sg2 = (tid & 1) * 32;
#pragma unroll
      for (int k = 0; k < 4; ++k)
        *(bf16x8*)&Vl[d][sg2 + 8 * k] = *(const bf16x8*)(vs + (size_t)d * SKV + sg2 + 8 * k);
    } else {
      int s  = tid >> 2;
      int d0 = (tid & 3) * 32;
      int pb = btr[t * 2 + (s >> 5)];
      const float* ksrc = kc + (((size_t)pb * 32 + (s & 31)) * 8 + h) * 128 + d0;
#pragma unroll
      for (int k = 0; k < 4; ++k) {
        float4 a = *(const float4*)(ksrc + 8 * k);
        float4 c = *(const float4*)(ksrc + 8 * k + 4);
        *(bf16x8*)&Kl[s][d0 + 8 * k] = cvt8(a, c);
      }
      int d  = tid & 127;
      int sh = tid >> 7;
      int pbv = btr[t * 2 + sh];
      const float* vsrc = vc + (((size_t)pbv * 32) * 8 + h) * 128 + d;
#pragma unroll
      for (int k = 0; k < 8; ++k) {
        bf16x4 o;
#pragma unroll
        for (int j = 0; j < 4; ++j) o[j] = (bf16)vsrc[(size_t)(k * 4 + j) * 1024];
        *(bf16x4*)&Vl[d][sh * 32 + 4 * k] = o;
      }
    }
    __syncthreads();

    // ---- QK^T (swapped): S^T rows s = t*64+m*16+lg*4+r, col q = n*16+lq ----
    f32x4 accS[4][2];
#pragma unroll
    for (int m = 0; m < 4; ++m)
#pragma unroll
      for (int n = 0; n < 2; ++n) accS[m][n] = zero;
#pragma unroll
    for (int m = 0; m < 4; ++m) {
      bf16x8 ak[4];
#pragma unroll
      for (int kk = 0; kk < 4; ++kk)
        ak[kk] = *(const bf16x8*)&Kl[m * 16 + lq][kk * 32 + lg * 8];
#pragma unroll
      for (int n = 0; n < 2; ++n)
#pragma unroll
        for (int kk = 0; kk < 4; ++kk)
          accS[m][n] = __builtin_amdgcn_mfma_f32_16x16x32_bf16(ak[kk], qf[n][kk], accS[m][n], 0, 0, 0);
    }

    // ---- causal mask: only boundary tiles need it ----
    if (t * KVB + KVB - 1 > ctx + lb) {
#pragma unroll
      for (int m = 0; m < 4; ++m) {
        int sg = t * 64 + m * 16 + lg * 4;
#pragma unroll
        for (int n = 0; n < 2; ++n) {
          int qpos = ctx + lb + n * 16 + lq;
#pragma unroll
          for (int r = 0; r < 4; ++r)
            if (sg + r > qpos) accS[m][n][r] = -1e30f;
        }
      }
    }

    // ---- online softmax (per q column = lane&15) ----
#pragma unroll
    for (int n = 0; n < 2; ++n) {
      float mx = accS[0][n][0];
#pragma unroll
      for (int m = 0; m < 4; ++m)
#pragma unroll
        for (int r = 0; r < 4; ++r) mx = fmaxf(mx, accS[m][n][r]);
      mx = fmaxf(mx, __shfl_xor(mx, 16));
      mx = fmaxf(mx, __shfl_xor(mx, 32));
      float mnew = fmaxf(mrun[n], mx);
      float corr = exp2f((mrun[n] - mnew) * CEXP);
      mrun[n] = mnew;
      float psum = 0.f;
#pragma unroll
      for (int m = 0; m < 4; ++m) {
        bf16x4 pk;
#pragma unroll
        for (int r = 0; r < 4; ++r) {
          float p = exp2f((accS[m][n][r] - mnew) * CEXP);
          psum += p;
          pk[r] = (bf16)p;
        }
        *(bf16x4*)&Pl[w][n * 16 + lq][m * 16 + lg * 4] = pk;
      }
      lrun[n] = lrun[n] * corr + psum;   // per-lane partial sum (reduced at end)
      // rescale accO rows q = n*16 + lg*4 + r (broadcast corr from lane lg*4+r)
      float cb[4];
#pragma unroll
      for (int r = 0; r < 4; ++r) cb[r] = __shfl(corr, lg * 4 + r);
#pragma unroll
      for (int nd = 0; nd < 8; ++nd)
#pragma unroll
        for (int r = 0; r < 4; ++r) accO[n][nd][r] *= cb[r];
    }

    // P written/read within the same wave only: drain LDS queue
    asm volatile("s_waitcnt lgkmcnt(0)" ::: "memory");

    // ---- PV: out[q][d] += P[q][s] * V[s][d] ----
    bf16x8 ap[2][2];
#pragma unroll
    for (int m2 = 0; m2 < 2; ++m2)
#pragma unroll
      for (int ks = 0; ks < 2; ++ks)
        ap[m2][ks] = *(const bf16x8*)&Pl[w][m2 * 16 + lq][ks * 32 + lg * 8];
#pragma unroll
    for (int nd = 0; nd < 8; ++nd) {
      bf16x8 bv0 = *(const bf16x8*)&Vl[nd * 16 + lq][lg * 8];
      bf16x8 bv1 = *(const bf16x8*)&Vl[nd * 16 + lq][32 + lg * 8];
#pragma unroll
      for (int m2 = 0; m2 < 2; ++m2) {
        accO[m2][nd] = __builtin_amdgcn_mfma_f32_16x16x32_bf16(ap[m2][0], bv0, accO[m2][nd], 0, 0, 0);
        accO[m2][nd] = __builtin_amdgcn_mfma_f32_16x16x32_bf16(ap[m2][1], bv1, accO[m2][nd], 0, 0, 0);
      }
    }
    __syncthreads();
  }

  // ---- epilogue: finish row sums, normalize, store f32 ----
#pragma unroll
  for (int n = 0; n < 2; ++n) {
    lrun[n] += __shfl_xor(lrun[n], 16);
    lrun[n] += __shfl_xor(lrun[n], 32);
    lrun[n] = 1.f / lrun[n];
  }
#pragma unroll
  for (int m2 = 0; m2 < 2; ++m2) {
    float rb[4];
#pragma unroll
    for (int r = 0; r < 4; ++r) rb[r] = __shfl(lrun[m2], lg * 4 + r);
#pragma unroll
    for (int r = 0; r < 4; ++r) {
      float* op = out + (((size_t)(b * LQ + lb + m2 * 16 + lg * 4 + r)) * HQN + hq) * DH + lq;
#pragma unroll
      for (int nd = 0; nd < 8; ++nd) op[nd * 16] = accO[m2][nd][r] * rb[r];
    }
  }
}

extern "C" void kernel_launch(void* const* d_in, const int* in_sizes, int n_in,
                              void* d_out, int out_size, void* d_ws, size_t ws_size,
                              hipStream_t stream) {
  const float* q  = (const float*)d_in[0];
  const float* kc = (const float*)d_in[1];
  const float* vc = (const float*)d_in[2];
  const int* bt   = (const int*)d_in[3];
  const int* sl   = (const int*)d_in[4];
  float* out = (float*)d_out;

  size_t half = (size_t)NSEQ * HKVN * SKV * DH;       // elements of one bf16 array
  size_t need = 2 * half * sizeof(bf16);              // 32 MiB
  if (ws_size >= need) {
    bf16* kb = (bf16*)d_ws;
    bf16* vt = kb + half;
    hipLaunchKernelGGL(prep_k, dim3(4096), dim3(256), 0, stream, kc, bt, kb);
    hipLaunchKernelGGL(prep_vt, dim3(1024), dim3(256), 0, stream, vc, bt, vt);
    hipLaunchKernelGGL((attn_kern<true>), dim3(512), dim3(256), 0, stream,
                       q, kc, vc, bt, sl, kb, vt, out);
  } else {
    hipLaunchKernelGGL((attn_kern<false>), dim3(512), dim3(256), 0, stream,
                       q, kc, vc, bt, sl, (const bf16*)nullptr, (const bf16*)nullptr, out);
  }
}

// Round 2
// 123.590 us; speedup vs baseline: 1.1090x; 1.1090x over previous
//
#include <hip/hip_runtime.h>
#include <hip/hip_bf16.h>

typedef __bf16 bf16;
typedef __attribute__((ext_vector_type(8))) __bf16 bf16x8;
typedef __attribute__((ext_vector_type(4))) __bf16 bf16x4;
typedef __attribute__((ext_vector_type(4))) float f32x4;

static constexpr int NSEQ = 4;
static constexpr int LQ   = 512;
static constexpr int HQN  = 32;
static constexpr int HKVN = 8;
static constexpr int GQ   = 4;
static constexpr int DH   = 128;
static constexpr int BPS  = 64;     // blocks per sequence (2048/32)
static constexpr int SKV  = 2048;   // max kv length
static constexpr int KVB  = 64;     // kv tile (2 paged blocks)
static constexpr int QBL  = 32;     // l-rows per workgroup (per wave, 1 g head each)

__device__ __forceinline__ bf16x8 cvt8(const float4& a, const float4& b) {
  bf16x8 o;
  o[0] = (bf16)a.x; o[1] = (bf16)a.y; o[2] = (bf16)a.z; o[3] = (bf16)a.w;
  o[4] = (bf16)b.x; o[5] = (bf16)b.y; o[6] = (bf16)b.z; o[7] = (bf16)b.w;
  return o;
}

// prepass 1: gather paged K + convert to bf16: kb[b][h][s][d]
__global__ void prep_k(const float* __restrict__ kc, const int* __restrict__ bt,
                       bf16* __restrict__ kb) {
  int e = (blockIdx.x * 256 + threadIdx.x) * 8;   // 8 elems / thread
  int d = e & 127;
  int s = (e >> 7) & 2047;
  int h = (e >> 18) & 7;
  int b = e >> 21;
  int pb = bt[b * BPS + (s >> 5)];
  const float* src = kc + (((size_t)pb * 32 + (s & 31)) * 8 + h) * 128 + d;
  float4 a = *(const float4*)src;
  float4 c = *(const float4*)(src + 4);
  *(bf16x8*)(kb + e) = cvt8(a, c);
}

// prepass 2: gather paged V + convert + transpose: vt[b][h][d][s]
__global__ void prep_vt(const float* __restrict__ vc, const int* __restrict__ bt,
                        bf16* __restrict__ vt) {
  __shared__ __align__(16) bf16 T[64][136];
  int bid = blockIdx.x;          // 4*8*32 = 1024 blocks
  int st = bid & 31;
  int h  = (bid >> 5) & 7;
  int b  = bid >> 8;
  int tid = threadIdx.x;
  {
    int s  = tid >> 2;
    int d0 = (tid & 3) * 32;
    int sg = st * 64 + s;
    int pb = bt[b * BPS + (sg >> 5)];
    const float* src = vc + (((size_t)pb * 32 + (sg & 31)) * 8 + h) * 128 + d0;
#pragma unroll
    for (int k = 0; k < 4; ++k) {
      float4 a = *(const float4*)(src + 8 * k);
      float4 c = *(const float4*)(src + 8 * k + 4);
      *(bf16x8*)&T[s][d0 + 8 * k] = cvt8(a, c);
    }
  }
  __syncthreads();
  {
    int d  = tid & 127;
    int g2 = tid >> 7;
    bf16* dst = vt + (((size_t)(b * 8 + h)) * 128 + d) * SKV + st * 64 + g2 * 32;
#pragma unroll
    for (int k = 0; k < 4; ++k) {
      bf16x8 o;
#pragma unroll
      for (int j = 0; j < 8; ++j) o[j] = T[g2 * 32 + k * 8 + j][d];
      *(bf16x8*)(dst + 8 * k) = o;
    }
  }
}

// flash attention: 1 workgroup = (b, h, 32 l-rows); wave w handles GQA head g = w.
// Swapped QK^T (A=K, B=Q) -> S^T; softmax in-register (defer-max T13); P through
// per-wave LDS; PV with A=P, B=V^T from LDS. Async-split K/V prefetch (T14).
template <bool WS>
__global__ __launch_bounds__(256, 2)
void attn_kern(const float* __restrict__ q, const float* __restrict__ kc,
               const float* __restrict__ vc, const int* __restrict__ bt,
               const int* __restrict__ seq_lens, const bf16* __restrict__ kb,
               const bf16* __restrict__ vtb, float* __restrict__ out) {
  __shared__ __align__(16) bf16 Kl[64][136];      // [s][d], pad -> conflict-light
  __shared__ __align__(16) bf16 Vl[128][72];      // [d][s] (transposed V)
  __shared__ __align__(16) bf16 Pl[4][32][72];    // per wave [q][s]

  // bid mapping: bid & bid+256 are complementary qtiles (work sum const = 57 tiles),
  // 4 (b,h) combos per XCD residue for L2 locality.
  int bid = (int)blockIdx.x;
  int hi  = bid >> 8;
  int u   = bid & 255;
  int xcd = u & 7;
  int k2  = u >> 3;
  int c   = (k2 >> 3) | (xcd << 2);   // (b,h) combo 0..31
  int i   = k2 & 7;
  int qt  = hi ? (15 - i) : i;
  int h   = c & 7;
  int b   = c >> 3;
  int lb  = qt * QBL;

  int tid  = (int)threadIdx.x;
  int w    = tid >> 6;       // g head
  int lane = tid & 63;
  int lq   = lane & 15;
  int lg   = lane >> 4;

  int ctx = seq_lens[b] - LQ;                       // 1536
  int nt  = (ctx + lb + QBL + KVB - 1) / KVB;       // kv tiles needed (causal)

  const float CEXP = 0.08838834764831843f * 1.44269504088896340f;  // scale*log2(e)
  const float TH8  = 8.0f / CEXP;                   // defer-max threshold (raw units)

  // Q fragments (B-operand): lane holds Q[lb + n*16 + lq][kk*32 + lg*8 + j]
  int hq = h * GQ + w;
  bf16x8 qf[2][4];
#pragma unroll
  for (int n = 0; n < 2; ++n) {
    const float* qp = q + (((size_t)(b * LQ + lb + n * 16 + lq)) * HQN + hq) * DH + lg * 8;
#pragma unroll
    for (int kk = 0; kk < 4; ++kk) {
      float4 a = *(const float4*)(qp + kk * 32);
      float4 c2 = *(const float4*)(qp + kk * 32 + 4);
      qf[n][kk] = cvt8(a, c2);
    }
  }

  f32x4 accO[2][8];
  f32x4 zero = {0.f, 0.f, 0.f, 0.f};
#pragma unroll
  for (int m = 0; m < 2; ++m)
#pragma unroll
    for (int nd = 0; nd < 8; ++nd) accO[m][nd] = zero;
  float mrun[2] = {-1e30f, -1e30f};
  float lrun[2] = {0.f, 0.f};

  const int* btr = bt + b * BPS;
  const bf16* kbase = WS ? kb  + (size_t)(b * 8 + h) * SKV * DH : nullptr;
  const bf16* vbase = WS ? vtb + (size_t)(b * 8 + h) * DH * SKV : nullptr;

  // staging geometry
  int ks_ = tid >> 2, kd0 = (tid & 3) * 32;   // K: [s][d] rows
  int vd_ = tid >> 1, vs0 = (tid & 1) * 32;   // V^T: [d][s] rows

  bf16x8 kpre[4], vpre[4];
  auto ldKV = [&](int t) {
    const bf16* ks = kbase + ((size_t)t * 64 + ks_) * DH + kd0;
#pragma unroll
    for (int k = 0; k < 4; ++k) kpre[k] = *(const bf16x8*)(ks + 8 * k);
    const bf16* vs = vbase + (size_t)vd_ * SKV + t * 64 + vs0;
#pragma unroll
    for (int k = 0; k < 4; ++k) vpre[k] = *(const bf16x8*)(vs + 8 * k);
  };
  auto stKV = [&]() {
#pragma unroll
    for (int k = 0; k < 4; ++k) *(bf16x8*)&Kl[ks_][kd0 + 8 * k] = kpre[k];
#pragma unroll
    for (int k = 0; k < 4; ++k) *(bf16x8*)&Vl[vd_][vs0 + 8 * k] = vpre[k];
  };

  auto compute = [&](int t) {
    // ---- QK^T (swapped): S^T rows s = t*64+m*16+lg*4+r, col q = n*16+lq ----
    f32x4 accS[4][2];
#pragma unroll
    for (int m = 0; m < 4; ++m)
#pragma unroll
      for (int n = 0; n < 2; ++n) accS[m][n] = zero;
#pragma unroll
    for (int m = 0; m < 4; ++m) {
      bf16x8 ak[4];
#pragma unroll
      for (int kk = 0; kk < 4; ++kk)
        ak[kk] = *(const bf16x8*)&Kl[m * 16 + lq][kk * 32 + lg * 8];
#pragma unroll
      for (int n = 0; n < 2; ++n)
#pragma unroll
        for (int kk = 0; kk < 4; ++kk)
          accS[m][n] = __builtin_amdgcn_mfma_f32_16x16x32_bf16(ak[kk], qf[n][kk], accS[m][n], 0, 0, 0);
    }

    // ---- causal mask: only boundary tiles need it ----
    if (t * KVB + KVB - 1 > ctx + lb) {
#pragma unroll
      for (int m = 0; m < 4; ++m) {
        int sg = t * 64 + m * 16 + lg * 4;
#pragma unroll
        for (int n = 0; n < 2; ++n) {
          int qpos = ctx + lb + n * 16 + lq;
#pragma unroll
          for (int r = 0; r < 4; ++r)
            if (sg + r > qpos) accS[m][n][r] = -1e30f;
        }
      }
    }

    // ---- online softmax (per q column = lane&15), defer-max ----
#pragma unroll
    for (int n = 0; n < 2; ++n) {
      float mx = accS[0][n][0];
#pragma unroll
      for (int m = 0; m < 4; ++m)
#pragma unroll
        for (int r = 0; r < 4; ++r) mx = fmaxf(mx, accS[m][n][r]);
      mx = fmaxf(mx, __shfl_xor(mx, 16));
      mx = fmaxf(mx, __shfl_xor(mx, 32));
      if (!__all(mx <= mrun[n] + TH8)) {
        float mnew = fmaxf(mrun[n], mx);
        float corr = exp2f((mrun[n] - mnew) * CEXP);
        mrun[n] = mnew;
        lrun[n] *= corr;
        float cb[4];
#pragma unroll
        for (int r = 0; r < 4; ++r) cb[r] = __shfl(corr, lg * 4 + r);
#pragma unroll
        for (int nd = 0; nd < 8; ++nd)
#pragma unroll
          for (int r = 0; r < 4; ++r) accO[n][nd][r] *= cb[r];
      }
      float psum = 0.f;
#pragma unroll
      for (int m = 0; m < 4; ++m) {
        bf16x4 pk;
#pragma unroll
        for (int r = 0; r < 4; ++r) {
          float p = exp2f((accS[m][n][r] - mrun[n]) * CEXP);
          psum += p;
          pk[r] = (bf16)p;
        }
        *(bf16x4*)&Pl[w][n * 16 + lq][m * 16 + lg * 4] = pk;
      }
      lrun[n] += psum;   // per-lane partial sum (reduced at end)
    }

    // P written/read within the same wave only: drain LDS queue
    asm volatile("s_waitcnt lgkmcnt(0)" ::: "memory");

    // ---- PV: out[q][d] += P[q][s] * V[s][d] ----
    bf16x8 ap[2][2];
#pragma unroll
    for (int m2 = 0; m2 < 2; ++m2)
#pragma unroll
      for (int ks3 = 0; ks3 < 2; ++ks3)
        ap[m2][ks3] = *(const bf16x8*)&Pl[w][m2 * 16 + lq][ks3 * 32 + lg * 8];
#pragma unroll
    for (int nd = 0; nd < 8; ++nd) {
      bf16x8 bv0 = *(const bf16x8*)&Vl[nd * 16 + lq][lg * 8];
      bf16x8 bv1 = *(const bf16x8*)&Vl[nd * 16 + lq][32 + lg * 8];
#pragma unroll
      for (int m2 = 0; m2 < 2; ++m2) {
        accO[m2][nd] = __builtin_amdgcn_mfma_f32_16x16x32_bf16(ap[m2][0], bv0, accO[m2][nd], 0, 0, 0);
        accO[m2][nd] = __builtin_amdgcn_mfma_f32_16x16x32_bf16(ap[m2][1], bv1, accO[m2][nd], 0, 0, 0);
      }
    }
  };

  if (WS) {
    // prologue: stage tile 0
    ldKV(0);
    stKV();
    __syncthreads();
    for (int t = 0; t < nt; ++t) {
      bool more = (t + 1 < nt);
      if (more) ldKV(t + 1);       // loads in flight across compute (T14)
      compute(t);
      if (more) {
        __syncthreads();           // all waves done reading tile t
        stKV();                    // implicit vmcnt wait here, not at loop top
        __syncthreads();
      }
    }
  } else {
    for (int t = 0; t < nt; ++t) {
      // direct gather from paged f32 caches (fallback, no workspace)
      {
        int s  = tid >> 2;
        int d0 = (tid & 3) * 32;
        int pb = btr[t * 2 + (s >> 5)];
        const float* ksrc = kc + (((size_t)pb * 32 + (s & 31)) * 8 + h) * 128 + d0;
#pragma unroll
        for (int k = 0; k < 4; ++k) {
          float4 a = *(const float4*)(ksrc + 8 * k);
          float4 c2 = *(const float4*)(ksrc + 8 * k + 4);
          *(bf16x8*)&Kl[s][d0 + 8 * k] = cvt8(a, c2);
        }
        int d  = tid & 127;
        int sh = tid >> 7;
        int pbv = btr[t * 2 + sh];
        const float* vsrc = vc + (((size_t)pbv * 32) * 8 + h) * 128 + d;
#pragma unroll
        for (int k = 0; k < 8; ++k) {
          bf16x4 o;
#pragma unroll
          for (int j = 0; j < 4; ++j) o[j] = (bf16)vsrc[(size_t)(k * 4 + j) * 1024];
          *(bf16x4*)&Vl[d][sh * 32 + 4 * k] = o;
        }
      }
      __syncthreads();
      compute(t);
      __syncthreads();
    }
  }

  // ---- epilogue: finish row sums, normalize, store f32 ----
#pragma unroll
  for (int n = 0; n < 2; ++n) {
    lrun[n] += __shfl_xor(lrun[n], 16);
    lrun[n] += __shfl_xor(lrun[n], 32);
    lrun[n] = 1.f / lrun[n];
  }
#pragma unroll
  for (int m2 = 0; m2 < 2; ++m2) {
    float rb[4];
#pragma unroll
    for (int r = 0; r < 4; ++r) rb[r] = __shfl(lrun[m2], lg * 4 + r);
#pragma unroll
    for (int r = 0; r < 4; ++r) {
      float* op = out + (((size_t)(b * LQ + lb + m2 * 16 + lg * 4 + r)) * HQN + hq) * DH + lq;
#pragma unroll
      for (int nd = 0; nd < 8; ++nd) op[nd * 16] = accO[m2][nd][r] * rb[r];
    }
  }
}

extern "C" void kernel_launch(void* const* d_in, const int* in_sizes, int n_in,
                              void* d_out, int out_size, void* d_ws, size_t ws_size,
                              hipStream_t stream) {
  const float* q  = (const float*)d_in[0];
  const float* kc = (const float*)d_in[1];
  const float* vc = (const float*)d_in[2];
  const int* bt   = (const int*)d_in[3];
  const int* sl   = (const int*)d_in[4];
  float* out = (float*)d_out;

  size_t half = (size_t)NSEQ * HKVN * SKV * DH;       // elements of one bf16 array
  size_t need = 2 * half * sizeof(bf16);              // 32 MiB
  if (ws_size >= need) {
    bf16* kb = (bf16*)d_ws;
    bf16* vt = kb + half;
    hipLaunchKernelGGL(prep_k, dim3(4096), dim3(256), 0, stream, kc, bt, kb);
    hipLaunchKernelGGL(prep_vt, dim3(1024), dim3(256), 0, stream, vc, bt, vt);
    hipLaunchKernelGGL((attn_kern<true>), dim3(512), dim3(256), 0, stream,
                       q, kc, vc, bt, sl, kb, vt, out);
  } else {
    hipLaunchKernelGGL((attn_kern<false>), dim3(512), dim3(256), 0, stream,
                       q, kc, vc, bt, sl, (const bf16*)nullptr, (const bf16*)nullptr, out);
  }
}